// Round 7
// baseline (389.225 us; speedup 1.0000x reference)
//
#include <hip/hip_runtime.h>

// MPLayer: out[i,m] = (1/K) sum_{j,l,n} edges[i,j,n] * nodes[nlist[i,j],l] * w[l,m,n]
// N=50000, K=32, F=128, E=16. Two-phase MFMA (fp16 in, fp32 acc):
//   phase 1: T[i][c'] (permuted c-order), per 16-wide l-tile one 16x16x32 MFMA
//   phase 2: out = T @ W2t^T / K, with W2t columns stored in the SAME permuted order
// v7: v6 (VERIFIED 334.9us bench / 198us k_mp) + depth-4 gather prefetch ring.
//   Counters (r6): MfmaUtil 6.6%, VALUBusy 7.1%, HBM 23.6%, occ 36% -> pure
//   latency-bound; Little's law with depth-1 prefetch (2 loads in flight)
//   reproduces the measured 1.9 TB/s. Fix = MLP: pf[4] register ring,
//   - rows 0..3 of chunk ch+1 issued at END of phase 2 (nothing issued after
//     them -> no in-order vmcnt drain by w2t consumes; they ride over the
//     barrier into next phase 1),
//   - rows 4..7 issued during phase-1 r=0..3 into freed slots (covered by
//     ~4 iterations of LDS+MFMA work each).
//   All pf indices compile-time (rule 20). Staging/transpose/T-store/phase-2
//   byte-identical to v6. LDS 40KB, __launch_bounds__(256,4).

typedef _Float16 half8  __attribute__((ext_vector_type(8)));
typedef _Float16 half4v __attribute__((ext_vector_type(4)));
typedef float    float4v __attribute__((ext_vector_type(4)));
typedef int      int4v  __attribute__((ext_vector_type(4)));
typedef unsigned int uint;

#define NF 128
#define NK 32
#define NE 16
#define RPB 32

__global__ __launch_bounds__(256) void k_prep_nodes(const float* __restrict__ src,
                                                    _Float16* __restrict__ dst, int n4) {
    int i = blockIdx.x * 256 + threadIdx.x;
    if (i < n4) {
        float4v v = ((const float4v*)src)[i];
        half4v h;
        h[0] = (_Float16)v[0]; h[1] = (_Float16)v[1];
        h[2] = (_Float16)v[2]; h[3] = (_Float16)v[3];
        ((half4v*)dst)[i] = h;
    }
}

// W2t permuted: storage index o = m*2048 + ch*512 + ltq*64 + n*4 + g
// corresponds to w[l, m, n] with l = ch*32 + (ltq>>2)*16 + (ltq&3)*4 + g.
__global__ __launch_bounds__(256) void k_prep_w(const float* __restrict__ w,
                                                _Float16* __restrict__ w2t) {
    int o  = blockIdx.x * 256 + threadIdx.x;   // 262144 total, exact grid
    int m  = o >> 11;
    int cf = o & 2047;
    int ch = cf >> 9;
    int cp = cf & 511;
    int ltq = cp >> 6;
    int n   = (cp >> 2) & 15;
    int g   = cp & 3;
    int l = ch * 32 + (ltq >> 2) * 16 + (ltq & 3) * 4 + g;
    w2t[o] = (_Float16)w[(l * NF + m) * NE + n];
}

// MFMA 16x16x32 f16 layouts (verified by v1/v2/v6 passing):
//   A: lane holds A[m = lane&15][k = (lane>>4)*8 + jj]
//   B: lane holds B[k = (lane>>4)*8 + jj][n = lane&15]
//   C/D: lane holds D[row = (lane>>4)*4 + g][col = lane&15]
__global__ __launch_bounds__(256, 4) void k_mp(const _Float16* __restrict__ nodes_h,
                                               const int* __restrict__ nlist,
                                               const float* __restrict__ edges,
                                               const _Float16* __restrict__ w2t,
                                               float* __restrict__ out, int N) {
    // s_T: 32 i-rows x 512 permuted-c halves per chunk, XOR-swizzled (32KB).
    // s_G: per-wave gather staging, 32 j-rows x 32 cols, block-XOR by j>>3 (8KB).
    __shared__ __align__(16) _Float16 s_T[RPB * 512];
    __shared__ __align__(16) _Float16 s_G[4 * NK * 32];

    const int tid  = threadIdx.x;
    const int wv   = tid >> 6;
    const int ln   = tid & 63;
    const int quad = ln >> 4;
    const int c16  = ln & 15;
    const int row0 = blockIdx.x * RPB;

    _Float16* __restrict__ gbuf = &s_G[wv * (NK * 32)];
    const float4v zf = {0.f, 0.f, 0.f, 0.f};

    // ---- edge B-fragments (persistent across chunks) ----
    half8 fe[8];
    #pragma unroll
    for (int r = 0; r < 8; ++r) {
        int rg = row0 + wv * 8 + r; if (rg > N - 1) rg = N - 1;
        const float* ep = edges + (size_t)rg * (NK * NE) + quad * (8 * NE) + c16;
        #pragma unroll
        for (int jj = 0; jj < 8; ++jj) fe[r][jj] = (_Float16)ep[jj * NE];
    }

    // ---- neighbor row byte-offsets: lane stages rows j=jlane and jlane+16 ----
    const int jlane = ln >> 2;       // 0..15
    const int sub   = ln & 3;        // which 16B piece of the 64B chunk-row
    int nb0[8], nb1[8];
    #pragma unroll
    for (int r = 0; r < 8; ++r) {
        int rg = row0 + wv * 8 + r; if (rg > N - 1) rg = N - 1;
        nb0[r] = nlist[rg * NK + jlane]      << 8;   // *256 bytes per fp16 node row
        nb1[r] = nlist[rg * NK + 16 + jlane] << 8;
    }
    // staging write blocks, XOR by (j>>3)&3 (matches read side where j>>3 == quad)
    const int wblk0 = (sub ^ ((jlane >> 3) & 3)) << 3;
    const int wblk1 = (sub ^ (((jlane + 16) >> 3) & 3)) << 3;

    float4v a00 = zf, a01 = zf, a10 = zf, a11 = zf;
    const char* nbase = (const char*)nodes_h;

    // ---- depth-4 register prefetch ring (all indices compile-time) ----
    half8 pf0[4], pf1[4];
    #pragma unroll
    for (int r0 = 0; r0 < 4; ++r0) {               // chunk 0, rows 0..3
        pf0[r0] = *(const half8*)(nbase + nb0[r0] + sub * 16);
        pf1[r0] = *(const half8*)(nbase + nb1[r0] + sub * 16);
    }

    for (int ch = 0; ch < 4; ++ch) {
        // ================= phase 1 =================
        #pragma unroll
        for (int r = 0; r < 8; ++r) {
            const int il = wv * 8 + r;
            // consume ring slot r&3 (compiler inserts the incremental vmcnt wait)
            half8 g0 = pf0[r & 3];
            half8 g1 = pf1[r & 3];
            if (r < 4) {                           // refill slot with row r+4, this chunk
                pf0[r & 3] = *(const half8*)(nbase + nb0[r + 4] + ch * 64 + sub * 16);
                pf1[r & 3] = *(const half8*)(nbase + nb1[r + 4] + ch * 64 + sub * 16);
            }
            *(half8*)&gbuf[jlane * 32 + wblk0]        = g0;
            *(half8*)&gbuf[(jlane + 16) * 32 + wblk1] = g1;
            // per-wave buffer: LDS ops from one wave complete in order; no barrier
            #pragma unroll
            for (int lt = 0; lt < 2; ++lt) {
                const int col   = lt * 16 + c16;
                const int rbase = quad * (8 * 32) + (col ^ (quad << 3));
                uint t0 = *(const unsigned short*)&gbuf[rbase + 0 * 32];
                uint t1 = *(const unsigned short*)&gbuf[rbase + 1 * 32];
                uint t2 = *(const unsigned short*)&gbuf[rbase + 2 * 32];
                uint t3 = *(const unsigned short*)&gbuf[rbase + 3 * 32];
                uint t4 = *(const unsigned short*)&gbuf[rbase + 4 * 32];
                uint t5 = *(const unsigned short*)&gbuf[rbase + 5 * 32];
                uint t6 = *(const unsigned short*)&gbuf[rbase + 6 * 32];
                uint t7 = *(const unsigned short*)&gbuf[rbase + 7 * 32];
                int4v pv;
                pv[0] = (int)(t0 | (t1 << 16));
                pv[1] = (int)(t2 | (t3 << 16));
                pv[2] = (int)(t4 | (t5 << 16));
                pv[3] = (int)(t6 | (t7 << 16));
                half8 av = __builtin_bit_cast(half8, pv);
                float4v d = __builtin_amdgcn_mfma_f32_16x16x32_f16(av, fe[r], zf, 0, 0, 0);
                // T store, permuted: c' = ltq*64 + c16*4 + g  (g contiguous -> b64)
                const int ltq  = lt * 4 + quad;
                const int cb   = ltq * 64 + c16 * 4;
                const int phys = cb ^ ((((ltq ^ il) & 7)) << 3);
                half4v hv;
                hv[0] = (_Float16)d[0]; hv[1] = (_Float16)d[1];
                hv[2] = (_Float16)d[2]; hv[3] = (_Float16)d[3];
                *(half4v*)&s_T[il * 512 + phys] = hv;
            }
        }
        __syncthreads();

        // ================= phase 2 =================
        const _Float16* wr0 = w2t + ((size_t)(wv * 2 + 0) * 16 + c16) * 2048 + ch * 512;
        const _Float16* wr1 = w2t + ((size_t)(wv * 2 + 1) * 16 + c16) * 2048 + ch * 512;
        #pragma unroll 4
        for (int kt = 0; kt < 16; ++kt) {
            const int cb2  = kt * 32 + quad * 8;
            const int mask = (((cb2 >> 6) ^ c16) & 7) << 3;
            half8 t0 = *(const half8*)&s_T[c16 * 512        + (cb2 ^ mask)];
            half8 t1 = *(const half8*)&s_T[(16 + c16) * 512 + (cb2 ^ mask)];
            half8 b0 = *(const half8*)(wr0 + cb2);
            half8 b1 = *(const half8*)(wr1 + cb2);
            a00 = __builtin_amdgcn_mfma_f32_16x16x32_f16(t0, b0, a00, 0, 0, 0);
            a10 = __builtin_amdgcn_mfma_f32_16x16x32_f16(t1, b0, a10, 0, 0, 0);
            a01 = __builtin_amdgcn_mfma_f32_16x16x32_f16(t0, b1, a01, 0, 0, 0);
            a11 = __builtin_amdgcn_mfma_f32_16x16x32_f16(t1, b1, a11, 0, 0, 0);
        }
        // ---- issue rows 0..3 of next chunk LAST (nothing issued after them,
        //      so phase-2's w2t consumes never drain them; they ride over the
        //      barrier and land during next phase-1's preamble) ----
        if (ch < 3) {
            #pragma unroll
            for (int r0 = 0; r0 < 4; ++r0) {
                pf0[r0] = *(const half8*)(nbase + nb0[r0] + (ch + 1) * 64 + sub * 16);
                pf1[r0] = *(const half8*)(nbase + nb1[r0] + (ch + 1) * 64 + sub * 16);
            }
        }
        __syncthreads();   // before next chunk's phase 1 overwrites s_T
    }

    // ---- epilogue ----
    const float sc = 1.0f / (float)NK;
    const int mb = (wv << 5) + c16;
    #pragma unroll
    for (int g = 0; g < 4; ++g) {
        int i0 = row0 + quad * 4 + g;
        int i1 = i0 + 16;
        if (i0 < N) {
            out[(size_t)i0 * NF + mb]      = a00[g] * sc;
            out[(size_t)i0 * NF + mb + 16] = a01[g] * sc;
        }
        if (i1 < N) {
            out[(size_t)i1 * NF + mb]      = a10[g] * sc;
            out[(size_t)i1 * NF + mb + 16] = a11[g] * sc;
        }
    }
}

extern "C" void kernel_launch(void* const* d_in, const int* in_sizes, int n_in,
                              void* d_out, int out_size, void* d_ws, size_t ws_size,
                              hipStream_t stream) {
    const float* nodes = (const float*)d_in[0];
    const int*   nlist = (const int*)d_in[1];
    const float* edges = (const float*)d_in[2];
    const float* w     = (const float*)d_in[3];
    float* out = (float*)d_out;

    const int N = in_sizes[0] / NF;   // 50000

    _Float16* w2t     = (_Float16*)d_ws;                       // 512KB
    _Float16* nodes_h = (_Float16*)((char*)d_ws + 524288);     // 12.8MB

    const int n4 = (N * NF) / 4;
    k_prep_nodes<<<(n4 + 255) / 256, 256, 0, stream>>>(nodes, nodes_h, n4);
    k_prep_w<<<(NF * NF * NE) / 256, 256, 0, stream>>>(w, w2t);

    const int blocks = (N + RPB - 1) / RPB;                    // 1563
    k_mp<<<blocks, 256, 0, stream>>>(nodes_h, nlist, edges, w2t, out, N);
}

// Round 9
// 369.140 us; speedup vs baseline: 1.0544x; 1.0544x over previous
//
#include <hip/hip_runtime.h>

// MPLayer: out[i,m] = (1/K) sum_{j,l,n} edges[i,j,n] * nodes[nlist[i,j],l] * w[l,m,n]
// N=50000, K=32, F=128, E=16. Two-phase MFMA (fp16 in, fp32 acc):
//   phase 1: T[i][c'] (permuted c-order), per 16-wide l-tile one 16x16x32 MFMA
//   phase 2: out = T @ W2t^T / K, with W2t columns in the SAME permuted order
// v8 (resubmit after broker timeout; full layout re-audit passed):
//   byte-reduction round (v7 post-mortem: BW pinned at ~1.93 TB/s; dur tracks
//   bytes moved; gather fetched each 128B node line TWICE, half-used each time;
//   epilogue's scattered 64B writes amplified WRITE_SIZE 2.25x).
//   - NCH=2 chunks of 64 l's: gather reads full 128B lines exactly once
//     (row 256B = line A [l 0..63] + line B [l 64..127]).  gather ~205->~102MB.
//   - RPB=16 (N/16=3125 exact, no tail): s_T = 16x1024 halves (32KB),
//     s_G = 4 waves x 32 rows x 64 halves (16KB) -> 48KB -> 3 blocks/CU.
//   - epilogue staged through s_T (dead) as float[16][128], then one contiguous
//     8KB block write -> full-line WRITE, ~57.7->~27MB.
//   - issue pattern = v6's verified depth-1 (consume pf, issue r+1, cross-chunk
//     prefetch after phase-1 barrier). No new intrinsics, no asm.

typedef _Float16 half8  __attribute__((ext_vector_type(8)));
typedef _Float16 half4v __attribute__((ext_vector_type(4)));
typedef float    float4v __attribute__((ext_vector_type(4)));
typedef int      int4v  __attribute__((ext_vector_type(4)));
typedef unsigned int uint;

#define NF 128
#define NK 32
#define NE 16
#define RPB 16

__global__ __launch_bounds__(256) void k_prep_nodes(const float* __restrict__ src,
                                                    _Float16* __restrict__ dst, int n4) {
    int i = blockIdx.x * 256 + threadIdx.x;
    if (i < n4) {
        float4v v = ((const float4v*)src)[i];
        half4v h;
        h[0] = (_Float16)v[0]; h[1] = (_Float16)v[1];
        h[2] = (_Float16)v[2]; h[3] = (_Float16)v[3];
        ((half4v*)dst)[i] = h;
    }
}

// W2t permuted (64-l chunks): o = m*2048 + ch*1024 + ltq*64 + n*4 + g
// corresponds to w[l, m, n] with l = ch*64 + (ltq>>2)*16 + (ltq&3)*4 + g.
// (v6's verified mapping with ch blocks widened 512->1024, ltq 0..15.)
__global__ __launch_bounds__(256) void k_prep_w(const float* __restrict__ w,
                                                _Float16* __restrict__ w2t) {
    int o   = blockIdx.x * 256 + threadIdx.x;   // 262144 total, exact grid
    int m   = o >> 11;
    int cf  = o & 2047;
    int ch  = cf >> 10;
    int cp  = cf & 1023;
    int ltq = cp >> 6;
    int n   = (cp >> 2) & 15;
    int g   = cp & 3;
    int l = ch * 64 + (ltq >> 2) * 16 + (ltq & 3) * 4 + g;
    w2t[o] = (_Float16)w[(l * NF + m) * NE + n];
}

// MFMA 16x16x32 f16 layouts (verified v1/v2/v6):
//   A: lane holds A[m = lane&15][k = (lane>>4)*8 + jj]
//   B: lane holds B[k = (lane>>4)*8 + jj][n = lane&15]
//   C/D: lane holds D[row = (lane>>4)*4 + g][col = lane&15]
//
// gbuf (per wave, 32 rows x 64 halves = 4KB): logical col c of row j stored at
//   physical col c ^ ((j>>3)<<3)   (same XOR family as v6, now 8 col-blocks).
// Gather (per r): load t in 0..3 covers row j_t = t*8 + (ln>>3), piece s8=ln&7
//   (16B = cols s8*8..+8). Physical block = (s8 ^ t) since j_t>>3 == t.
// Transpose read (quad q reads rows q*8+jj, col lt*16+c16):
//   addr = (q*8+jj)*64 + ((lt*16+c16) ^ (q<<3)); piece index (lt*2+(c16>>3))^q
//   matches the store XOR at t=q. Same bank behavior family as verified v6.
__global__ __launch_bounds__(256, 3) void k_mp(const _Float16* __restrict__ nodes_h,
                                               const int* __restrict__ nlist,
                                               const float* __restrict__ edges,
                                               const _Float16* __restrict__ w2t,
                                               float* __restrict__ out, int N) {
    __shared__ __align__(16) _Float16 s_T[RPB * 1024];    // 32 KB
    __shared__ __align__(16) _Float16 s_G[4 * 2048];      // 16 KB

    const int tid  = threadIdx.x;
    const int wv   = tid >> 6;
    const int ln   = tid & 63;
    const int quad = ln >> 4;
    const int c16  = ln & 15;
    const int row0 = blockIdx.x * RPB;

    _Float16* __restrict__ gbuf = &s_G[wv * 2048];
    const float4v zf = {0.f, 0.f, 0.f, 0.f};

    // ---- edge B-fragments (4 i-rows per wave) ----
    half8 fe[4];
    #pragma unroll
    for (int r = 0; r < 4; ++r) {
        int rg = row0 + wv * 4 + r; if (rg > N - 1) rg = N - 1;
        const float* ep = edges + (size_t)rg * (NK * NE) + quad * (8 * NE) + c16;
        #pragma unroll
        for (int jj = 0; jj < 8; ++jj) fe[r][jj] = (_Float16)ep[jj * NE];
    }

    // ---- neighbor byte-offsets: lane's 4 rows are t*8 + (ln>>3), t=0..3 ----
    const int jrow = ln >> 3;        // 0..7
    const int s8   = ln & 7;         // 16B piece within the 128B line
    int nb0[4], nb1[4], nb2[4], nb3[4];
    #pragma unroll
    for (int r = 0; r < 4; ++r) {
        int rg = row0 + wv * 4 + r; if (rg > N - 1) rg = N - 1;
        const int* np = nlist + rg * NK + jrow;
        nb0[r] = np[0]  << 8;        // *256 bytes per fp16 node row
        nb1[r] = np[8]  << 8;
        nb2[r] = np[16] << 8;
        nb3[r] = np[24] << 8;
    }
    const char* nbase = (const char*)nodes_h + (s8 << 4);

    // staging dest offsets (halves), physical col-block = s8 ^ t:
    const int wo0 = (0 * 8 + jrow) * 64 + ((s8 ^ 0) << 3);
    const int wo1 = (1 * 8 + jrow) * 64 + ((s8 ^ 1) << 3);
    const int wo2 = (2 * 8 + jrow) * 64 + ((s8 ^ 2) << 3);
    const int wo3 = (3 * 8 + jrow) * 64 + ((s8 ^ 3) << 3);

    float4v a00 = zf, a01 = zf;

    // ---- prefetch ch=0, r=0 (4 x 16B) ----
    half8 pf0 = *(const half8*)(nbase + nb0[0]);
    half8 pf1 = *(const half8*)(nbase + nb1[0]);
    half8 pf2 = *(const half8*)(nbase + nb2[0]);
    half8 pf3 = *(const half8*)(nbase + nb3[0]);

    for (int ch = 0; ch < 2; ++ch) {
        const int chb = ch << 7;     // 128B: line A or line B of each node row

        // ================= phase 1 =================
        #pragma unroll
        for (int r = 0; r < 4; ++r) {
            half8 g0 = pf0, g1 = pf1, g2 = pf2, g3 = pf3;
            if (r < 3) {             // issue next i-row's line loads before use
                pf0 = *(const half8*)(nbase + nb0[r + 1] + chb);
                pf1 = *(const half8*)(nbase + nb1[r + 1] + chb);
                pf2 = *(const half8*)(nbase + nb2[r + 1] + chb);
                pf3 = *(const half8*)(nbase + nb3[r + 1] + chb);
            }
            *(half8*)&gbuf[wo0] = g0;
            *(half8*)&gbuf[wo1] = g1;
            *(half8*)&gbuf[wo2] = g2;
            *(half8*)&gbuf[wo3] = g3;
            // per-wave buffer, in-order LDS: no barrier needed
            const int il = wv * 4 + r;
            #pragma unroll
            for (int lt = 0; lt < 4; ++lt) {
                const int rbase = quad * 512 + ((lt * 16 + c16) ^ (quad << 3));
                uint t0 = *(const unsigned short*)&gbuf[rbase + 0 * 64];
                uint t1 = *(const unsigned short*)&gbuf[rbase + 1 * 64];
                uint t2 = *(const unsigned short*)&gbuf[rbase + 2 * 64];
                uint t3 = *(const unsigned short*)&gbuf[rbase + 3 * 64];
                uint t4 = *(const unsigned short*)&gbuf[rbase + 4 * 64];
                uint t5 = *(const unsigned short*)&gbuf[rbase + 5 * 64];
                uint t6 = *(const unsigned short*)&gbuf[rbase + 6 * 64];
                uint t7 = *(const unsigned short*)&gbuf[rbase + 7 * 64];
                int4v pv;
                pv[0] = (int)(t0 | (t1 << 16));
                pv[1] = (int)(t2 | (t3 << 16));
                pv[2] = (int)(t4 | (t5 << 16));
                pv[3] = (int)(t6 | (t7 << 16));
                half8 av = __builtin_bit_cast(half8, pv);
                float4v d = __builtin_amdgcn_mfma_f32_16x16x32_f16(av, fe[r], zf, 0, 0, 0);
                // T store: c' = ltq*64 + c16*4 + g, XOR-swizzled by i-row
                const int ltq  = lt * 4 + quad;
                const int cb   = ltq * 64 + c16 * 4;
                const int phys = cb ^ (((ltq ^ il) & 7) << 3);
                half4v hv;
                hv[0] = (_Float16)d[0]; hv[1] = (_Float16)d[1];
                hv[2] = (_Float16)d[2]; hv[3] = (_Float16)d[3];
                *(half4v*)&s_T[il * 1024 + phys] = hv;
            }
        }
        __syncthreads();

        // ---- prefetch next chunk's r=0; lands during phase 2's MFMAs ----
        if (ch == 0) {
            pf0 = *(const half8*)(nbase + nb0[0] + 128);
            pf1 = *(const half8*)(nbase + nb1[0] + 128);
            pf2 = *(const half8*)(nbase + nb2[0] + 128);
            pf3 = *(const half8*)(nbase + nb3[0] + 128);
        }

        // ================= phase 2 =================
        const _Float16* wr0 = w2t + ((size_t)(wv * 2 + 0) * 16 + c16) * 2048 + ch * 1024;
        const _Float16* wr1 = w2t + ((size_t)(wv * 2 + 1) * 16 + c16) * 2048 + ch * 1024;
        #pragma unroll 4
        for (int kt = 0; kt < 32; ++kt) {
            const int cb2  = kt * 32 + quad * 8;
            const int mask = (((cb2 >> 6) ^ c16) & 7) << 3;
            half8 t0 = *(const half8*)&s_T[c16 * 1024 + (cb2 ^ mask)];
            half8 b0 = *(const half8*)(wr0 + cb2);
            half8 b1 = *(const half8*)(wr1 + cb2);
            a00 = __builtin_amdgcn_mfma_f32_16x16x32_f16(t0, b0, a00, 0, 0, 0);
            a01 = __builtin_amdgcn_mfma_f32_16x16x32_f16(t0, b1, a01, 0, 0, 0);
        }
        __syncthreads();   // before next chunk's phase 1 / epilogue reuse of s_T
    }

    // ---- epilogue: stage through s_T (dead) -> one contiguous 8KB block write ----
    float* sf = (float*)s_T;
    const float sc = 1.0f / (float)NK;
    const int mb = (wv << 5) + c16;
    #pragma unroll
    for (int g = 0; g < 4; ++g) {
        sf[(quad * 4 + g) * NF + mb]      = a00[g] * sc;
        sf[(quad * 4 + g) * NF + mb + 16] = a01[g] * sc;
    }
    __syncthreads();
    const int lim = (N - row0) * NF;             // floats valid (inert: N%16==0)
    float* ob = out + (size_t)row0 * NF;
    #pragma unroll
    for (int u = 0; u < 2; ++u) {
        const int idx = (tid + u * 256) * 4;
        if (idx < lim) *(float4v*)&ob[idx] = *(const float4v*)&sf[idx];
    }
}

extern "C" void kernel_launch(void* const* d_in, const int* in_sizes, int n_in,
                              void* d_out, int out_size, void* d_ws, size_t ws_size,
                              hipStream_t stream) {
    const float* nodes = (const float*)d_in[0];
    const int*   nlist = (const int*)d_in[1];
    const float* edges = (const float*)d_in[2];
    const float* w     = (const float*)d_in[3];
    float* out = (float*)d_out;

    const int N = in_sizes[0] / NF;   // 50000

    _Float16* w2t     = (_Float16*)d_ws;                       // 512KB
    _Float16* nodes_h = (_Float16*)((char*)d_ws + 524288);     // 12.8MB

    const int n4 = (N * NF) / 4;
    k_prep_nodes<<<(n4 + 255) / 256, 256, 0, stream>>>(nodes, nodes_h, n4);
    k_prep_w<<<(NF * NF * NE) / 256, 256, 0, stream>>>(w, w2t);

    const int blocks = (N + RPB - 1) / RPB;                    // 3125
    k_mp<<<blocks, 256, 0, stream>>>(nodes_h, nlist, edges, w2t, out, N);
}

// Round 10
// 326.440 us; speedup vs baseline: 1.1923x; 1.1308x over previous
//
#include <hip/hip_runtime.h>

// MPLayer: out[i,m] = (1/K) sum_{j,l,n} edges[i,j,n] * nodes[nlist[i,j],l] * w[l,m,n]
// N=50000, K=32, F=128, E=16. Two-phase MFMA (fp16 in, fp32 acc):
//   phase 1: T[i][c'] (permuted c-order), per 16-wide l-tile one 16x16x32 MFMA
//   phase 2: out = T @ W2t^T / K, with W2t columns stored in the SAME permuted order
// v9 = v6 structure (best measured: 198us k_mp, 4 blocks/CU) + two edits:
//   (1) depth-2 SCALAR prefetch (pA/pB pairs, alternating by r&1, all names
//       static -> no v7-style scratch spill): loads for r+2 issue right after
//       r's pair is consumed by the staging write; next chunk's r=0 AND r=1
//       pairs issue before phase-2's kt loop (ride over all 64 MFMAs).
//   (2) LDS-staged epilogue (v8-verified, WRITE 57.7->25.0MB): acc -> dead s_T
//       as float[32][128], then one contiguous 16KB block write.
// Post-mortem basis (r9): v8 cut bytes exactly as predicted (394->211 fetch,
//   89->25 write) but got SLOWER (198->237us, BW 1.0TB/s, all pipes <13%) ->
//   NOT BW-bound; per-block serial gather-latency chain + occupancy dominate.
//   v7's ring: bytes +27% at flat VGPR=64 = scratch spill (rule-20 tell).
// LDS 40KB -> 4 blocks/CU, __launch_bounds__(256,4).

typedef _Float16 half8  __attribute__((ext_vector_type(8)));
typedef _Float16 half4v __attribute__((ext_vector_type(4)));
typedef float    float4v __attribute__((ext_vector_type(4)));
typedef int      int4v  __attribute__((ext_vector_type(4)));
typedef unsigned int uint;

#define NF 128
#define NK 32
#define NE 16
#define RPB 32

__global__ __launch_bounds__(256) void k_prep_nodes(const float* __restrict__ src,
                                                    _Float16* __restrict__ dst, int n4) {
    int i = blockIdx.x * 256 + threadIdx.x;
    if (i < n4) {
        float4v v = ((const float4v*)src)[i];
        half4v h;
        h[0] = (_Float16)v[0]; h[1] = (_Float16)v[1];
        h[2] = (_Float16)v[2]; h[3] = (_Float16)v[3];
        ((half4v*)dst)[i] = h;
    }
}

// W2t permuted: storage index o = m*2048 + ch*512 + ltq*64 + n*4 + g
// corresponds to w[l, m, n] with l = ch*32 + (ltq>>2)*16 + (ltq&3)*4 + g.
__global__ __launch_bounds__(256) void k_prep_w(const float* __restrict__ w,
                                                _Float16* __restrict__ w2t) {
    int o  = blockIdx.x * 256 + threadIdx.x;   // 262144 total, exact grid
    int m  = o >> 11;
    int cf = o & 2047;
    int ch = cf >> 9;
    int cp = cf & 511;
    int ltq = cp >> 6;
    int n   = (cp >> 2) & 15;
    int g   = cp & 3;
    int l = ch * 32 + (ltq >> 2) * 16 + (ltq & 3) * 4 + g;
    w2t[o] = (_Float16)w[(l * NF + m) * NE + n];
}

// MFMA 16x16x32 f16 layouts (verified v1/v2/v6):
//   A: lane holds A[m = lane&15][k = (lane>>4)*8 + jj]
//   B: lane holds B[k = (lane>>4)*8 + jj][n = lane&15]
//   C/D: lane holds D[row = (lane>>4)*4 + g][col = lane&15]
__global__ __launch_bounds__(256, 4) void k_mp(const _Float16* __restrict__ nodes_h,
                                               const int* __restrict__ nlist,
                                               const float* __restrict__ edges,
                                               const _Float16* __restrict__ w2t,
                                               float* __restrict__ out, int N) {
    // s_T: 32 i-rows x 512 permuted-c halves per chunk, XOR-swizzled (32KB).
    // s_G: per-wave gather staging, 32 j-rows x 32 cols, block-XOR by j>>3 (8KB).
    __shared__ __align__(16) _Float16 s_T[RPB * 512];
    __shared__ __align__(16) _Float16 s_G[4 * NK * 32];

    const int tid  = threadIdx.x;
    const int wv   = tid >> 6;
    const int ln   = tid & 63;
    const int quad = ln >> 4;
    const int c16  = ln & 15;
    const int row0 = blockIdx.x * RPB;

    _Float16* __restrict__ gbuf = &s_G[wv * (NK * 32)];
    const float4v zf = {0.f, 0.f, 0.f, 0.f};

    // ---- edge B-fragments (persistent across chunks) ----
    half8 fe[8];
    #pragma unroll
    for (int r = 0; r < 8; ++r) {
        int rg = row0 + wv * 8 + r; if (rg > N - 1) rg = N - 1;
        const float* ep = edges + (size_t)rg * (NK * NE) + quad * (8 * NE) + c16;
        #pragma unroll
        for (int jj = 0; jj < 8; ++jj) fe[r][jj] = (_Float16)ep[jj * NE];
    }

    // ---- neighbor row byte-offsets: lane stages rows j=jlane and jlane+16 ----
    const int jlane = ln >> 2;       // 0..15
    const int sub   = ln & 3;        // which 16B piece of the 64B chunk-row
    int nb0[8], nb1[8];
    #pragma unroll
    for (int r = 0; r < 8; ++r) {
        int rg = row0 + wv * 8 + r; if (rg > N - 1) rg = N - 1;
        nb0[r] = nlist[rg * NK + jlane]      << 8;   // *256 bytes per fp16 node row
        nb1[r] = nlist[rg * NK + 16 + jlane] << 8;
    }
    // staging write blocks, XOR by (j>>3)&3 (matches read side where j>>3 == quad)
    const int wblk0 = (sub ^ ((jlane >> 3) & 3)) << 3;
    const int wblk1 = (sub ^ (((jlane + 16) >> 3) & 3)) << 3;

    float4v a00 = zf, a01 = zf, a10 = zf, a11 = zf;
    const char* nbase = (const char*)nodes_h;

    // ---- depth-2 scalar prefetch: pA = pair for even r, pB = pair for odd r ----
    half8 pA0 = *(const half8*)(nbase + nb0[0] + sub * 16);
    half8 pA1 = *(const half8*)(nbase + nb1[0] + sub * 16);
    half8 pB0 = *(const half8*)(nbase + nb0[1] + sub * 16);
    half8 pB1 = *(const half8*)(nbase + nb1[1] + sub * 16);

    for (int ch = 0; ch < 4; ++ch) {
        // ================= phase 1 =================
        #pragma unroll
        for (int r = 0; r < 8; ++r) {
            const int il = wv * 8 + r;
            // consume this r's pair via the staging write (vmcnt wait lands here,
            // for a load issued 2 iterations ago), then immediately reissue the
            // freed slot for r+2 -> ~2 iterations of latency cover.
            if ((r & 1) == 0) {
                *(half8*)&gbuf[jlane * 32 + wblk0]        = pA0;
                *(half8*)&gbuf[(jlane + 16) * 32 + wblk1] = pA1;
                if (r < 6) {
                    pA0 = *(const half8*)(nbase + nb0[r + 2] + ch * 64 + sub * 16);
                    pA1 = *(const half8*)(nbase + nb1[r + 2] + ch * 64 + sub * 16);
                }
            } else {
                *(half8*)&gbuf[jlane * 32 + wblk0]        = pB0;
                *(half8*)&gbuf[(jlane + 16) * 32 + wblk1] = pB1;
                if (r < 6) {
                    pB0 = *(const half8*)(nbase + nb0[r + 2] + ch * 64 + sub * 16);
                    pB1 = *(const half8*)(nbase + nb1[r + 2] + ch * 64 + sub * 16);
                }
            }
            // per-wave buffer: LDS ops from one wave complete in order; no barrier
            #pragma unroll
            for (int lt = 0; lt < 2; ++lt) {
                const int col   = lt * 16 + c16;
                const int rbase = quad * (8 * 32) + (col ^ (quad << 3));
                uint t0 = *(const unsigned short*)&gbuf[rbase + 0 * 32];
                uint t1 = *(const unsigned short*)&gbuf[rbase + 1 * 32];
                uint t2 = *(const unsigned short*)&gbuf[rbase + 2 * 32];
                uint t3 = *(const unsigned short*)&gbuf[rbase + 3 * 32];
                uint t4 = *(const unsigned short*)&gbuf[rbase + 4 * 32];
                uint t5 = *(const unsigned short*)&gbuf[rbase + 5 * 32];
                uint t6 = *(const unsigned short*)&gbuf[rbase + 6 * 32];
                uint t7 = *(const unsigned short*)&gbuf[rbase + 7 * 32];
                int4v pv;
                pv[0] = (int)(t0 | (t1 << 16));
                pv[1] = (int)(t2 | (t3 << 16));
                pv[2] = (int)(t4 | (t5 << 16));
                pv[3] = (int)(t6 | (t7 << 16));
                half8 av = __builtin_bit_cast(half8, pv);
                float4v d = __builtin_amdgcn_mfma_f32_16x16x32_f16(av, fe[r], zf, 0, 0, 0);
                // T store, permuted: c' = ltq*64 + c16*4 + g  (g contiguous -> b64)
                const int ltq  = lt * 4 + quad;
                const int cb   = ltq * 64 + c16 * 4;
                const int phys = cb ^ ((((ltq ^ il) & 7)) << 3);
                half4v hv;
                hv[0] = (_Float16)d[0]; hv[1] = (_Float16)d[1];
                hv[2] = (_Float16)d[2]; hv[3] = (_Float16)d[3];
                *(half4v*)&s_T[il * 512 + phys] = hv;
            }
        }
        __syncthreads();

        // ---- prefetch next chunk's r=0 and r=1 pairs (4 loads); they ride
        //      over phase 2's 64 MFMAs and land before next phase-1 starts ----
        if (ch < 3) {
            pA0 = *(const half8*)(nbase + nb0[0] + (ch + 1) * 64 + sub * 16);
            pA1 = *(const half8*)(nbase + nb1[0] + (ch + 1) * 64 + sub * 16);
            pB0 = *(const half8*)(nbase + nb0[1] + (ch + 1) * 64 + sub * 16);
            pB1 = *(const half8*)(nbase + nb1[1] + (ch + 1) * 64 + sub * 16);
        }

        // ================= phase 2 =================
        const _Float16* wr0 = w2t + ((size_t)(wv * 2 + 0) * 16 + c16) * 2048 + ch * 512;
        const _Float16* wr1 = w2t + ((size_t)(wv * 2 + 1) * 16 + c16) * 2048 + ch * 512;
        #pragma unroll 4
        for (int kt = 0; kt < 16; ++kt) {
            const int cb2  = kt * 32 + quad * 8;
            const int mask = (((cb2 >> 6) ^ c16) & 7) << 3;
            half8 t0 = *(const half8*)&s_T[c16 * 512        + (cb2 ^ mask)];
            half8 t1 = *(const half8*)&s_T[(16 + c16) * 512 + (cb2 ^ mask)];
            half8 b0 = *(const half8*)(wr0 + cb2);
            half8 b1 = *(const half8*)(wr1 + cb2);
            a00 = __builtin_amdgcn_mfma_f32_16x16x32_f16(t0, b0, a00, 0, 0, 0);
            a10 = __builtin_amdgcn_mfma_f32_16x16x32_f16(t1, b0, a10, 0, 0, 0);
            a01 = __builtin_amdgcn_mfma_f32_16x16x32_f16(t0, b1, a01, 0, 0, 0);
            a11 = __builtin_amdgcn_mfma_f32_16x16x32_f16(t1, b1, a11, 0, 0, 0);
        }
        __syncthreads();   // before next chunk's phase 1 overwrites s_T
    }

    // ---- epilogue: stage through s_T (dead) -> one contiguous 16KB block write ----
    float* sf = (float*)s_T;
    const float sc = 1.0f / (float)NK;
    const int mb = (wv << 5) + c16;
    #pragma unroll
    for (int g = 0; g < 4; ++g) {
        const int r0 = quad * 4 + g;
        sf[r0 * NF + mb]             = a00[g] * sc;
        sf[r0 * NF + mb + 16]        = a01[g] * sc;
        sf[(r0 + 16) * NF + mb]      = a10[g] * sc;
        sf[(r0 + 16) * NF + mb + 16] = a11[g] * sc;
    }
    __syncthreads();
    const int lim = (N - row0) * NF;             // floats valid (last block: 16 rows)
    float* ob = out + (size_t)row0 * NF;
    #pragma unroll
    for (int u = 0; u < 4; ++u) {
        const int idx = (tid + u * 256) * 4;
        if (idx < lim) *(float4v*)&ob[idx] = *(const float4v*)&sf[idx];
    }
}

extern "C" void kernel_launch(void* const* d_in, const int* in_sizes, int n_in,
                              void* d_out, int out_size, void* d_ws, size_t ws_size,
                              hipStream_t stream) {
    const float* nodes = (const float*)d_in[0];
    const int*   nlist = (const int*)d_in[1];
    const float* edges = (const float*)d_in[2];
    const float* w     = (const float*)d_in[3];
    float* out = (float*)d_out;

    const int N = in_sizes[0] / NF;   // 50000

    _Float16* w2t     = (_Float16*)d_ws;                       // 512KB
    _Float16* nodes_h = (_Float16*)((char*)d_ws + 524288);     // 12.8MB

    const int n4 = (N * NF) / 4;
    k_prep_nodes<<<(n4 + 255) / 256, 256, 0, stream>>>(nodes, nodes_h, n4);
    k_prep_w<<<(NF * NF * NE) / 256, 256, 0, stream>>>(w, w2t);

    const int blocks = (N + RPB - 1) / RPB;                    // 1563
    k_mp<<<blocks, 256, 0, stream>>>(nodes_h, nlist, edges, w2t, out, N);
}